// Round 1
// baseline (1215.711 us; speedup 1.0000x reference)
//
#include <hip/hip_runtime.h>
#include <cstdint>
#include <cstddef>

#define NN 25000
#define NE 400000
#define NFD 30
#define EFD 10
#define H 40
#define T 5
#define FO 8
#define LAYERS 2
#define TF 200          // T*F
#define BASE_W 800      // T*160
#define EPSV 1e-5f

// ---------- degree histogram ----------
__global__ __launch_bounds__(256) void k_deg(const int* __restrict__ dst, int* __restrict__ cnt) {
    int e = blockIdx.x * 256 + threadIdx.x;
    if (e < NE) atomicAdd(&cnt[dst[e]], 1);
}

// ---------- sum of log(cnt+1) ----------
__global__ __launch_bounds__(256) void k_avglog(const int* __restrict__ cnt, float* __restrict__ slot) {
    __shared__ float red[256];
    float s = 0.0f;
    for (int i = blockIdx.x * 256 + threadIdx.x; i < NN; i += gridDim.x * 256)
        s += logf((float)cnt[i] + 1.0f);
    red[threadIdx.x] = s; __syncthreads();
    for (int o = 128; o > 0; o >>= 1) {
        if (threadIdx.x < o) red[threadIdx.x] += red[threadIdx.x + o];
        __syncthreads();
    }
    if (threadIdx.x == 0) atomicAdd(slot, red[0]);
}

// ---------- per-node amp/att ----------
__global__ __launch_bounds__(256) void k_ampatt(const int* __restrict__ cnt, const float* __restrict__ slot,
                                                float* __restrict__ amp, float* __restrict__ att) {
    int i = blockIdx.x * 256 + threadIdx.x;
    if (i >= NN) return;
    float avg = slot[0] / (float)NN;
    float c1 = fmaxf((float)cnt[i], 1.0f);
    float lg = logf(c1 + 1.0f);
    amp[i] = lg / avg;
    att[i] = avg / lg;
}

// ---------- h0 = x @ node_w + node_b ----------
__global__ __launch_bounds__(256) void k_node_enc(const float* __restrict__ x, const float* __restrict__ w,
                                                  const float* __restrict__ b, float* __restrict__ h) {
    int id = blockIdx.x * 256 + threadIdx.x;
    if (id >= NN * H) return;
    int n = id / H, j = id - n * H;
    const float* xr = x + (size_t)n * NFD;
    float acc = b[j];
    #pragma unroll
    for (int m = 0; m < NFD; m++) acc += xr[m] * w[m * H + j];
    h[id] = acc;
}

// ---------- e_emb = edge_attr @ edge_w + edge_b ----------
__global__ __launch_bounds__(256) void k_edge_enc(const float* __restrict__ ea, const float* __restrict__ w,
                                                  const float* __restrict__ b, float* __restrict__ e_emb) {
    long long id = (long long)blockIdx.x * 256 + threadIdx.x;
    if (id >= (long long)NE * H) return;
    int e = (int)(id / H), j = (int)(id - (long long)e * H);
    const float* er = ea + (size_t)e * EFD;
    float acc = b[j];
    #pragma unroll
    for (int m = 0; m < EFD; m++) acc += er[m] * w[m * H + j];
    e_emb[id] = acc;
}

// ---------- exclusive scan of cnt -> offsets ----------
__global__ __launch_bounds__(1024) void k_scan(const int* __restrict__ cnt, int* __restrict__ offs) {
    __shared__ int buf[1024];
    __shared__ int running;
    if (threadIdx.x == 0) running = 0;
    __syncthreads();
    for (int base = 0; base < NN; base += 1024) {
        int i = base + threadIdx.x;
        int v = (i < NN) ? cnt[i] : 0;
        buf[threadIdx.x] = v;
        __syncthreads();
        for (int o = 1; o < 1024; o <<= 1) {
            int t = (threadIdx.x >= o) ? buf[threadIdx.x - o] : 0;
            __syncthreads();
            buf[threadIdx.x] += t;
            __syncthreads();
        }
        if (i < NN) offs[i] = running + buf[threadIdx.x] - v;
        __syncthreads();
        if (threadIdx.x == 1023) running += buf[1023];
        __syncthreads();
    }
    if (threadIdx.x == 0) offs[NN] = running;
}

// ---------- scatter edges into CSR ----------
__global__ __launch_bounds__(256) void k_scatter(const int* __restrict__ src, const int* __restrict__ dst,
                                                 const int* __restrict__ offs, int* __restrict__ fill,
                                                 int* __restrict__ csr_eid, int* __restrict__ csr_src) {
    int e = blockIdx.x * 256 + threadIdx.x;
    if (e >= NE) return;
    int d = dst[e];
    int p = offs[d] + atomicAdd(&fill[d], 1);
    csr_eid[p] = e;
    csr_src[p] = src[e];
}

// ---------- folded weights: W3'[m][j] = sum_o enc_w[m][o]*pre_w[t][80+o][f],  D[j] ----------
__global__ __launch_bounds__(256) void k_w3p(const float* __restrict__ enc_w, const float* __restrict__ enc_b,
                                             const float* __restrict__ pre_w, const float* __restrict__ pre_b,
                                             float* __restrict__ w3p, float* __restrict__ dvec, int layer) {
    int id = blockIdx.x * 256 + threadIdx.x;
    if (id >= H * TF) return;
    int m = id / TF, j = id - m * TF;
    int t = j / H, f = j - t * H;
    const float* ew = enc_w + (size_t)layer * H * H;
    const float* pw = pre_w + ((size_t)(layer * T + t) * 120) * H;
    float acc = 0.0f;
    #pragma unroll
    for (int o = 0; o < H; o++) acc += ew[m * H + o] * pw[(80 + o) * H + f];
    w3p[m * TF + j] = acc;
    if (m == 0) {
        const float* eb = enc_b + (size_t)layer * H;
        float dacc = pre_b[(size_t)(layer * T + t) * H + f];
        #pragma unroll
        for (int o = 0; o < H; o++) dacc += eb[o] * pw[(80 + o) * H + f];
        dvec[j] = dacc;
    }
}

// ---------- A = h@P1, B = h@P2  (one block per node) ----------
__global__ __launch_bounds__(256) void k_ab(const float* __restrict__ h, const float* __restrict__ pre_w,
                                            float* __restrict__ A, float* __restrict__ B, int layer) {
    __shared__ float sh[H];
    int n = blockIdx.x;
    if (threadIdx.x < H) sh[threadIdx.x] = h[(size_t)n * H + threadIdx.x];
    __syncthreads();
    int j = threadIdx.x;
    if (j >= TF) return;
    int t = j / H, f = j - t * H;
    const float* pw = pre_w + ((size_t)(layer * T + t) * 120) * H;
    float a = 0.0f, b = 0.0f;
    #pragma unroll
    for (int m = 0; m < H; m++) {
        float hv = sh[m];
        a += hv * pw[m * H + f];
        b += hv * pw[(H + m) * H + f];
    }
    A[(size_t)n * TF + j] = a;
    B[(size_t)n * TF + j] = b;
}

// ---------- aggregation: per node, per component j; u = B[src]+C+D ----------
__global__ __launch_bounds__(256) void k_agg(const float* __restrict__ e_emb, const float* __restrict__ B,
                                             const float* __restrict__ A, const float* __restrict__ w3p,
                                             const float* __restrict__ dvec, const int* __restrict__ cnt,
                                             const int* __restrict__ offs, const int* __restrict__ csr_eid,
                                             const int* __restrict__ csr_src, float* __restrict__ base) {
    int n = blockIdx.x;
    int j = threadIdx.x;
    if (j >= TF) return;
    float w3c[H];
    #pragma unroll
    for (int k = 0; k < H; k++) w3c[k] = w3p[k * TF + j];
    float dj = dvec[j];
    int deg = cnt[n];
    int start = offs[n];
    float s = 0.0f, q = 0.0f, mn = 3.4e38f, mx = -3.4e38f;
    for (int r = 0; r < deg; r++) {
        int eid = csr_eid[start + r];       // block-uniform -> scalar load
        int sn  = csr_src[start + r];       // block-uniform
        const float4* er4 = (const float4*)(e_emb + (size_t)eid * H);
        float C = dj;
        #pragma unroll
        for (int k4 = 0; k4 < H / 4; k4++) {
            float4 ev = er4[k4];            // uniform address -> s_load
            C += ev.x * w3c[k4 * 4] + ev.y * w3c[k4 * 4 + 1] +
                 ev.z * w3c[k4 * 4 + 2] + ev.w * w3c[k4 * 4 + 3];
        }
        float u = B[(size_t)sn * TF + j] + C;
        s += u; q += u * u;
        mn = fminf(mn, u); mx = fmaxf(mx, u);
    }
    float a = A[(size_t)n * TF + j];
    float d = (float)deg, c1 = fmaxf(d, 1.0f);
    float mean = (d * a + s) / c1;
    float msq  = (d * a * a + 2.0f * a * s + q) / c1;
    float sd   = sqrtf(fmaxf(msq - mean * mean, 0.0f) + EPSV);
    float mnv = (deg > 0) ? (a + mn) : 0.0f;
    float mxv = (deg > 0) ? (a + mx) : 0.0f;
    int t = j / H, f = j - t * H;
    float* bb = base + (size_t)n * BASE_W + t * 160 + f;
    bb[0]   = mean;
    bb[40]  = mnv;
    bb[80]  = mxv;
    bb[120] = sd;
}

// ---------- post einsum + lin  (6 nodes per 256-thread block, 40 lanes/node) ----------
__global__ __launch_bounds__(256) void k_post(const float* __restrict__ h, const float* __restrict__ base,
                                              const float* __restrict__ amp, const float* __restrict__ att,
                                              const float* __restrict__ post_w, const float* __restrict__ post_b,
                                              const float* __restrict__ lin_w, const float* __restrict__ lin_b,
                                              float* __restrict__ cbuf, int layer) {
    __shared__ float shx[6][H];
    __shared__ float sout[6][H];
    int local = threadIdx.x;
    int nl = local / H, q = local - nl * H;
    int n = blockIdx.x * 6 + nl;
    bool act = (nl < 6) && (n < NN);
    if (act) shx[nl][q] = h[(size_t)n * H + q];
    __syncthreads();
    if (act) {
        int t = q / FO, o = q - t * FO;
        const float* pw = post_w + ((size_t)(layer * T + t) * 520) * FO + o;
        float acc = post_b[(size_t)(layer * T + t) * FO + o];
        #pragma unroll
        for (int f = 0; f < H; f++) acc += shx[nl][f] * pw[f * FO];
        float am = amp[n], at = att[n];
        const float* br = base + (size_t)n * BASE_W + t * 160;
        for (int g = 0; g < 160; g++) {
            float w = pw[(40 + g) * FO] + am * pw[(200 + g) * FO] + at * pw[(360 + g) * FO];
            acc += br[g] * w;
        }
        sout[nl][q] = acc;
    }
    __syncthreads();
    if (act) {
        const float* lw = lin_w + (size_t)layer * H * H;
        float acc = lin_b[(size_t)layer * H + q];
        #pragma unroll
        for (int k = 0; k < H; k++) acc += sout[nl][k] * lw[k * H + q];
        cbuf[(size_t)n * H + q] = acc;
    }
}

// ---------- BN stats ----------
__global__ __launch_bounds__(320) void k_bnstats(const float* __restrict__ cbuf,
                                                 float* __restrict__ bnsum, float* __restrict__ bnsq) {
    __shared__ float ls[320], lq[320];
    int tid = threadIdx.x;
    int stride = gridDim.x * 320;        // multiple of 40
    float s = 0.0f, q = 0.0f;
    for (int idx = blockIdx.x * 320 + tid; idx < NN * H; idx += stride) {
        float v = cbuf[idx];
        s += v; q += v * v;
    }
    ls[tid] = s; lq[tid] = q;
    __syncthreads();
    if (tid < H) {
        float ss = 0.0f, qq = 0.0f;
        #pragma unroll
        for (int r = 0; r < 8; r++) { ss += ls[r * H + tid]; qq += lq[r * H + tid]; }
        atomicAdd(&bnsum[tid], ss);
        atomicAdd(&bnsq[tid], qq);
    }
}

// ---------- BN apply + residual ----------
__global__ __launch_bounds__(256) void k_bnapply(const float* __restrict__ cbuf, const float* __restrict__ bnsum,
                                                 const float* __restrict__ bnsq, const float* __restrict__ bn_g,
                                                 const float* __restrict__ bn_b, float* __restrict__ h, int layer) {
    int id = blockIdx.x * 256 + threadIdx.x;
    if (id >= NN * H) return;
    int j = id % H;
    float mu = bnsum[j] / (float)NN;
    float var = bnsq[j] / (float)NN - mu * mu;
    float inv = rsqrtf(var + EPSV);
    float cv = (cbuf[id] - mu) * inv * bn_g[(size_t)layer * H + j] + bn_b[(size_t)layer * H + j];
    h[id] = (h[id] + fmaxf(cv, 0.0f)) * 0.5f;
}

// ---------- final edge MLP (weights via uniform scalar loads) ----------
__global__ __launch_bounds__(256) void k_mlp(const float* __restrict__ h, const float* __restrict__ e_emb,
                                             const int* __restrict__ srcp, const int* __restrict__ dstp,
                                             const float* __restrict__ w1, const float* __restrict__ b1,
                                             const float* __restrict__ w2, const float* __restrict__ b2,
                                             const float* __restrict__ w3, const float* __restrict__ b3,
                                             float* __restrict__ out) {
    int e = blockIdx.x * 256 + threadIdx.x;
    if (e >= NE) return;
    int s = srcp[e], d = dstp[e];
    float z1[50];
    #pragma unroll
    for (int o = 0; o < 50; o++) z1[o] = b1[o];

    const float4* hr4 = (const float4*)(h + (size_t)s * H);
    for (int f4 = 0; f4 < H / 4; f4++) {
        float4 v4 = hr4[f4];
        float v0 = fmaxf(v4.x, 0.0f), v1 = fmaxf(v4.y, 0.0f), v2 = fmaxf(v4.z, 0.0f), v3 = fmaxf(v4.w, 0.0f);
        const float* wr = w1 + (f4 * 4) * 50;
        #pragma unroll
        for (int o = 0; o < 50; o++) z1[o] += v0 * wr[o] + v1 * wr[50 + o] + v2 * wr[100 + o] + v3 * wr[150 + o];
    }
    hr4 = (const float4*)(h + (size_t)d * H);
    for (int f4 = 0; f4 < H / 4; f4++) {
        float4 v4 = hr4[f4];
        float v0 = fmaxf(v4.x, 0.0f), v1 = fmaxf(v4.y, 0.0f), v2 = fmaxf(v4.z, 0.0f), v3 = fmaxf(v4.w, 0.0f);
        const float* wr = w1 + (H + f4 * 4) * 50;
        #pragma unroll
        for (int o = 0; o < 50; o++) z1[o] += v0 * wr[o] + v1 * wr[50 + o] + v2 * wr[100 + o] + v3 * wr[150 + o];
    }
    const float4* er4 = (const float4*)(e_emb + (size_t)e * H);
    for (int f4 = 0; f4 < H / 4; f4++) {
        float4 v4 = er4[f4];
        const float* wr = w1 + (2 * H + f4 * 4) * 50;
        #pragma unroll
        for (int o = 0; o < 50; o++) z1[o] += v4.x * wr[o] + v4.y * wr[50 + o] + v4.z * wr[100 + o] + v4.w * wr[150 + o];
    }

    float z2[25];
    #pragma unroll
    for (int o = 0; o < 25; o++) z2[o] = b2[o];
    #pragma unroll
    for (int k = 0; k < 50; k++) {
        float v = fmaxf(z1[k], 0.0f);
        #pragma unroll
        for (int o = 0; o < 25; o++) z2[o] += v * w2[k * 25 + o];
    }
    float o0 = b3[0], o1 = b3[1];
    #pragma unroll
    for (int k = 0; k < 25; k++) {
        float v = fmaxf(z2[k], 0.0f);
        o0 += v * w3[k * 2];
        o1 += v * w3[k * 2 + 1];
    }
    out[(size_t)e * 2]     = o0;
    out[(size_t)e * 2 + 1] = o1;
}

extern "C" void kernel_launch(void* const* d_in, const int* in_sizes, int n_in,
                              void* d_out, int out_size, void* d_ws, size_t ws_size,
                              hipStream_t stream) {
    const float* x         = (const float*)d_in[0];
    const float* edge_attr = (const float*)d_in[1];
    const int*   eidx      = (const int*)  d_in[2];
    const float* node_w    = (const float*)d_in[3];
    const float* node_b    = (const float*)d_in[4];
    const float* edge_w    = (const float*)d_in[5];
    const float* edge_b    = (const float*)d_in[6];
    const float* enc_w     = (const float*)d_in[7];
    const float* enc_b     = (const float*)d_in[8];
    const float* pre_w     = (const float*)d_in[9];
    const float* pre_b     = (const float*)d_in[10];
    const float* post_w    = (const float*)d_in[11];
    const float* post_b    = (const float*)d_in[12];
    const float* lin_w     = (const float*)d_in[13];
    const float* lin_b     = (const float*)d_in[14];
    const float* bn_g      = (const float*)d_in[15];
    const float* bn_b      = (const float*)d_in[16];
    const float* w1 = (const float*)d_in[17];
    const float* b1 = (const float*)d_in[18];
    const float* w2 = (const float*)d_in[19];
    const float* b2 = (const float*)d_in[20];
    const float* w3 = (const float*)d_in[21];
    const float* b3 = (const float*)d_in[22];
    const int* srcp = eidx;
    const int* dstp = eidx + NE;
    float* out = (float*)d_out;

    char* ws = (char*)d_ws;
    size_t off = 0;
    auto alloc = [&](size_t bytes) -> char* {
        char* p = ws + off;
        off += (bytes + 255) & ~(size_t)255;
        return p;
    };
    float* h     = (float*)alloc((size_t)NN * H * 4);
    float* e_emb = (float*)alloc((size_t)NE * H * 4);
    float* Abuf  = (float*)alloc((size_t)NN * TF * 4);
    float* Bbuf  = (float*)alloc((size_t)NN * TF * 4);
    float* base  = (float*)alloc((size_t)NN * BASE_W * 4);
    float* cbuf  = (float*)alloc((size_t)NN * H * 4);
    float* w3p   = (float*)alloc((size_t)H * TF * 4);
    float* dvec  = (float*)alloc((size_t)TF * 4);
    float* amp   = (float*)alloc((size_t)NN * 4);
    float* att   = (float*)alloc((size_t)NN * 4);
    float* avgs  = (float*)alloc(256);
    float* bnz   = (float*)alloc(512);   // [0:40) sum, [40:80) sumsq
    int* cnt_i   = (int*)alloc((size_t)NN * 4);
    int* offs    = (int*)alloc((size_t)(NN + 1) * 4);
    int* fill    = (int*)alloc((size_t)NN * 4);
    int* csr_eid = (int*)alloc((size_t)NE * 4);
    int* csr_src = (int*)alloc((size_t)NE * 4);
    if (off > ws_size) return;   // workspace too small — bail

    hipMemsetAsync(cnt_i, 0, (size_t)NN * 4, stream);
    hipMemsetAsync(fill, 0, (size_t)NN * 4, stream);
    hipMemsetAsync(avgs, 0, 4, stream);

    k_deg<<<(NE + 255) / 256, 256, 0, stream>>>(dstp, cnt_i);
    k_avglog<<<64, 256, 0, stream>>>(cnt_i, avgs);
    k_ampatt<<<(NN + 255) / 256, 256, 0, stream>>>(cnt_i, avgs, amp, att);
    k_node_enc<<<(NN * H + 255) / 256, 256, 0, stream>>>(x, node_w, node_b, h);
    k_edge_enc<<<(int)(((long long)NE * H + 255) / 256), 256, 0, stream>>>(edge_attr, edge_w, edge_b, e_emb);
    k_scan<<<1, 1024, 0, stream>>>(cnt_i, offs);
    k_scatter<<<(NE + 255) / 256, 256, 0, stream>>>(srcp, dstp, offs, fill, csr_eid, csr_src);

    for (int layer = 0; layer < LAYERS; layer++) {
        k_w3p<<<(H * TF + 255) / 256, 256, 0, stream>>>(enc_w, enc_b, pre_w, pre_b, w3p, dvec, layer);
        k_ab<<<NN, 256, 0, stream>>>(h, pre_w, Abuf, Bbuf, layer);
        k_agg<<<NN, 256, 0, stream>>>(e_emb, Bbuf, Abuf, w3p, dvec, cnt_i, offs, csr_eid, csr_src, base);
        k_post<<<(NN + 5) / 6, 256, 0, stream>>>(h, base, amp, att, post_w, post_b, lin_w, lin_b, cbuf, layer);
        hipMemsetAsync(bnz, 0, 320, stream);
        k_bnstats<<<64, 320, 0, stream>>>(cbuf, bnz, bnz + 40);
        k_bnapply<<<(NN * H + 255) / 256, 256, 0, stream>>>(cbuf, bnz, bnz + 40, bn_g, bn_b, h, layer);
    }
    k_mlp<<<(NE + 255) / 256, 256, 0, stream>>>(h, e_emb, srcp, dstp, w1, b1, w2, b2, w3, b3, out);
}